// Round 1
// baseline (387.485 us; speedup 1.0000x reference)
//
#include <hip/hip_runtime.h>
#include <hip/hip_bf16.h>

// PrototypeConsistentLearning: loss = mean(-pos + lse_neg), new_protos = serial EMA.
// B=8192, D=512, K=16384, T=0.5, momentum=0.9.
// Strategy: bf16 MFMA flash GEMM (no sim materialization, no online max needed since
// |sim|<=2), separate pos dot kernel, ballot-ordered exact serial EMA per cluster.

#define B_N 8192
#define D_N 512
#define K_N 16384
#define INV_T 2.0f
#define MOM 0.9f

#define BM 128
#define BN 128
#define BK 32
#define SPLIT 8

typedef __attribute__((ext_vector_type(8))) short short8;
typedef __attribute__((ext_vector_type(4))) float floatx4;

__device__ __forceinline__ unsigned short f2bf(float f) {
    // round-to-nearest-even fp32 -> bf16 (inputs are finite)
    unsigned int u = __float_as_uint(f);
    u += 0x7fffu + ((u >> 16) & 1u);
    return (unsigned short)(u >> 16);
}
__device__ __forceinline__ float bflo(unsigned int u) { return __uint_as_float(u << 16); }
__device__ __forceinline__ float bfhi(unsigned int u) { return __uint_as_float(u & 0xffff0000u); }

__device__ __forceinline__ void gl_lds16(const void* g, void* lds) {
    __builtin_amdgcn_global_load_lds(
        (const __attribute__((address_space(1))) void*)g,
        (__attribute__((address_space(3))) void*)lds, 16, 0, 0);
}

// ---- normalize rows (fp32 in) -> bf16 out. one wave per row of 512. ----
__global__ void norm_kernel(const float* __restrict__ x, unsigned short* __restrict__ out) {
    int row = blockIdx.x * 4 + (threadIdx.x >> 6);
    int lane = threadIdx.x & 63;
    const float4* xp = (const float4*)(x + (size_t)row * D_N + lane * 8);
    float4 v0 = xp[0];
    float4 v1 = xp[1];
    float ss = v0.x * v0.x + v0.y * v0.y + v0.z * v0.z + v0.w * v0.w +
               v1.x * v1.x + v1.y * v1.y + v1.z * v1.z + v1.w * v1.w;
    #pragma unroll
    for (int o = 32; o; o >>= 1) ss += __shfl_xor(ss, o);
    float inv = 1.0f / fmaxf(sqrtf(ss), 1e-12f);
    uint4 st;
    st.x = (unsigned)f2bf(v0.x * inv) | ((unsigned)f2bf(v0.y * inv) << 16);
    st.y = (unsigned)f2bf(v0.z * inv) | ((unsigned)f2bf(v0.w * inv) << 16);
    st.z = (unsigned)f2bf(v1.x * inv) | ((unsigned)f2bf(v1.y * inv) << 16);
    st.w = (unsigned)f2bf(v1.z * inv) | ((unsigned)f2bf(v1.w * inv) << 16);
    *(uint4*)(out + (size_t)row * D_N + lane * 8) = st;
}

// ---- pos[b] = dot(emb_n[b], proto_n[c_b]) * 2. one wave per row. ----
__global__ void pos_kernel(const unsigned short* __restrict__ embn,
                           const unsigned short* __restrict__ pron,
                           const int* __restrict__ cid, float* __restrict__ rowpos) {
    int b = blockIdx.x * 4 + (threadIdx.x >> 6);
    int lane = threadIdx.x & 63;
    int c = cid[b];
    uint4 ea = *(const uint4*)(embn + (size_t)b * D_N + lane * 8);
    uint4 pa = *(const uint4*)(pron + (size_t)c * D_N + lane * 8);
    float s = bflo(ea.x) * bflo(pa.x) + bfhi(ea.x) * bfhi(pa.x) +
              bflo(ea.y) * bflo(pa.y) + bfhi(ea.y) * bfhi(pa.y) +
              bflo(ea.z) * bflo(pa.z) + bfhi(ea.z) * bfhi(pa.z) +
              bflo(ea.w) * bflo(pa.w) + bfhi(ea.w) * bfhi(pa.w);
    #pragma unroll
    for (int o = 32; o; o >>= 1) s += __shfl_xor(s, o);
    if (lane == 0) rowpos[b] = s * INV_T;
}

// ---- flash GEMM: rowsum[b] += sum_k exp(2*dot(emb_n[b], proto_n[k])) ----
__global__ __launch_bounds__(256) void flash_kernel(const unsigned short* __restrict__ embn,
                                                    const unsigned short* __restrict__ pron,
                                                    float* __restrict__ rowsum_g) {
    __shared__ __align__(16) unsigned short As[BM * BK];
    __shared__ __align__(16) unsigned short Bs[BN * BK];
    const int t = threadIdx.x;
    const int w = t >> 6, lane = t & 63;
    const int quad = lane >> 4, lcol = lane & 15;
    const int wm = w >> 1, wn = w & 1;
    const int rowBase = blockIdx.x * BM;
    const int nBegin = blockIdx.y * (K_N / SPLIT);

    float rowsum[16];
    #pragma unroll
    for (int i = 0; i < 16; i++) rowsum[i] = 0.0f;

    for (int nt0 = 0; nt0 < K_N / SPLIT; nt0 += BN) {
        const int nBase = nBegin + nt0;
        floatx4 acc[4][4];
        #pragma unroll
        for (int mt = 0; mt < 4; mt++)
            #pragma unroll
            for (int nt = 0; nt < 4; nt++) {
                floatx4 z = {0.0f, 0.0f, 0.0f, 0.0f};
                acc[mt][nt] = z;
            }
        for (int d0 = 0; d0 < D_N; d0 += BK) {
            // stage A (128x32) and B (128x32) via async global->LDS, 16B/lane, 2 passes
            #pragma unroll
            for (int p = 0; p < 2; p++) {
                int flat = p * 256 + t;
                int r = flat >> 2, c16 = flat & 3;
                gl_lds16(embn + (size_t)(rowBase + r) * D_N + d0 + c16 * 8,
                         &As[(p * 256 + w * 64) * 8]);
                gl_lds16(pron + (size_t)(nBase + r) * D_N + d0 + c16 * 8,
                         &Bs[(p * 256 + w * 64) * 8]);
            }
            __syncthreads();
            short8 af[4], bf[4];
            #pragma unroll
            for (int mt = 0; mt < 4; mt++)
                af[mt] = *(const short8*)&As[(wm * 64 + mt * 16 + lcol) * BK + quad * 8];
            #pragma unroll
            for (int nt = 0; nt < 4; nt++)
                bf[nt] = *(const short8*)&Bs[(wn * 64 + nt * 16 + lcol) * BK + quad * 8];
            #pragma unroll
            for (int mt = 0; mt < 4; mt++)
                #pragma unroll
                for (int nt = 0; nt < 4; nt++)
                    acc[mt][nt] = __builtin_amdgcn_mfma_f32_16x16x32_bf16(af[mt], bf[nt],
                                                                          acc[mt][nt], 0, 0, 0);
            __syncthreads();
        }
        // epilogue: C/D layout col=lane&15, row=quad*4+reg
        #pragma unroll
        for (int mt = 0; mt < 4; mt++)
            #pragma unroll
            for (int nt = 0; nt < 4; nt++)
                #pragma unroll
                for (int r = 0; r < 4; r++)
                    rowsum[mt * 4 + r] += __expf(acc[mt][nt][r] * INV_T);
    }
    // reduce across the 16 lanes (same quad => same rows, different cols)
    #pragma unroll
    for (int i = 0; i < 16; i++) {
        #pragma unroll
        for (int o = 1; o < 16; o <<= 1) rowsum[i] += __shfl_xor(rowsum[i], o);
    }
    if (lcol == 0) {
        #pragma unroll
        for (int mt = 0; mt < 4; mt++)
            #pragma unroll
            for (int r = 0; r < 4; r++)
                atomicAdd(&rowsum_g[rowBase + wm * 64 + mt * 16 + quad * 4 + r],
                          rowsum[mt * 4 + r]);
    }
}

// ---- loss = mean(-pos + log(rowsum - exp(pos))) ----
__global__ void loss_kernel(const float* __restrict__ rowsum, const float* __restrict__ rowpos,
                            float* __restrict__ out) {
    __shared__ float red[256];
    int t = threadIdx.x;
    float s = 0.0f;
    for (int b = t; b < B_N; b += 256) {
        float p = rowpos[b];
        s += logf(rowsum[b] - __expf(p)) - p;
    }
    red[t] = s;
    __syncthreads();
    for (int o = 128; o; o >>= 1) {
        if (t < o) red[t] += red[t + o];
        __syncthreads();
    }
    if (t == 0) out[0] = red[0] * (1.0f / (float)B_N);
}

// ---- exact serial EMA: one wave per cluster, replay occurrences in order ----
__global__ void ema_kernel(const float* __restrict__ emb, const int* __restrict__ cid,
                           const float* __restrict__ pro, float* __restrict__ outp) {
    int k = blockIdx.x * 4 + (threadIdx.x >> 6);
    int lane = threadIdx.x & 63;
    float a[8];
    #pragma unroll
    for (int j = 0; j < 8; j++) a[j] = pro[(size_t)k * D_N + j * 64 + lane];
    for (int c0 = 0; c0 < B_N; c0 += 64) {
        int id = cid[c0 + lane];
        unsigned long long m = __ballot(id == k);
        while (m) {
            int bit = __ffsll(m) - 1;
            m &= m - 1;
            const float* e = emb + (size_t)(c0 + bit) * D_N;
            #pragma unroll
            for (int j = 0; j < 8; j++) a[j] = MOM * a[j] + (1.0f - MOM) * e[j * 64 + lane];
        }
    }
    #pragma unroll
    for (int j = 0; j < 8; j++) outp[(size_t)k * D_N + j * 64 + lane] = a[j];
}

extern "C" void kernel_launch(void* const* d_in, const int* in_sizes, int n_in,
                              void* d_out, int out_size, void* d_ws, size_t ws_size,
                              hipStream_t stream) {
    const float* emb = (const float*)d_in[0];
    const int* cid = (const int*)d_in[1];
    const float* pro = (const float*)d_in[2];
    float* out = (float*)d_out;

    char* ws = (char*)d_ws;
    unsigned short* embn = (unsigned short*)ws;                    // 8 MB bf16 [B,D]
    unsigned short* pron = (unsigned short*)(ws + 8388608);        // 16 MB bf16 [K,D]
    float* rowsum = (float*)(ws + 25165824);                       // [B]
    float* rowpos = (float*)(ws + 25198592);                       // [B]

    hipMemsetAsync(rowsum, 0, B_N * sizeof(float), stream);
    norm_kernel<<<B_N / 4, 256, 0, stream>>>(emb, embn);
    norm_kernel<<<K_N / 4, 256, 0, stream>>>(pro, pron);
    pos_kernel<<<B_N / 4, 256, 0, stream>>>(embn, pron, cid, rowpos);
    flash_kernel<<<dim3(B_N / BM, SPLIT), 256, 0, stream>>>(embn, pron, rowsum);
    loss_kernel<<<1, 256, 0, stream>>>(rowsum, rowpos, out);
    ema_kernel<<<K_N / 4, 256, 0, stream>>>(emb, cid, pro, out + 1);
}

// Round 2
// 380.341 us; speedup vs baseline: 1.0188x; 1.0188x over previous
//
#include <hip/hip_runtime.h>
#include <hip/hip_bf16.h>

// PrototypeConsistentLearning: loss = mean(-pos + lse_neg), new_protos = serial EMA.
// B=8192, D=512, K=16384, T=0.5, momentum=0.9.
// R2: SPLIT=16 (4 blocks/CU), XOR LDS swizzle (bank conflicts), bucket-replay EMA,
// fused norms, fp32 pos, multi-block loss.

#define B_N 8192
#define D_N 512
#define K_N 16384
#define INV_T 2.0f
#define MOM 0.9f
#define LOG2E_X2 2.8853900817779268f  // 2 * log2(e): exp(2a) = exp2(a * this)

#define BM 128
#define BN 128
#define BK 32
#define SPLIT 16
#define CAP 64

typedef __attribute__((ext_vector_type(8))) short short8;
typedef __attribute__((ext_vector_type(4))) float floatx4;

__device__ __forceinline__ unsigned short f2bf(float f) {
    unsigned int u = __float_as_uint(f);
    u += 0x7fffu + ((u >> 16) & 1u);
    return (unsigned short)(u >> 16);
}

__device__ __forceinline__ void gl_lds16(const void* g, void* lds) {
    __builtin_amdgcn_global_load_lds(
        (const __attribute__((address_space(1))) void*)g,
        (__attribute__((address_space(3))) void*)lds, 16, 0, 0);
}

// ---- normalize rows of emb and pro (fp32) -> bf16. one wave per row. ----
__global__ void norm_kernel(const float* __restrict__ emb, const float* __restrict__ pro,
                            unsigned short* __restrict__ embn, unsigned short* __restrict__ pron) {
    int row = blockIdx.x * 4 + (threadIdx.x >> 6);
    int lane = threadIdx.x & 63;
    const float* x;
    unsigned short* out;
    if (row < B_N) {
        x = emb + (size_t)row * D_N;
        out = embn + (size_t)row * D_N;
    } else {
        x = pro + (size_t)(row - B_N) * D_N;
        out = pron + (size_t)(row - B_N) * D_N;
    }
    const float4* xp = (const float4*)(x + lane * 8);
    float4 v0 = xp[0];
    float4 v1 = xp[1];
    float ss = v0.x * v0.x + v0.y * v0.y + v0.z * v0.z + v0.w * v0.w +
               v1.x * v1.x + v1.y * v1.y + v1.z * v1.z + v1.w * v1.w;
    #pragma unroll
    for (int o = 32; o; o >>= 1) ss += __shfl_xor(ss, o);
    float inv = 1.0f / fmaxf(sqrtf(ss), 1e-12f);
    uint4 st;
    st.x = (unsigned)f2bf(v0.x * inv) | ((unsigned)f2bf(v0.y * inv) << 16);
    st.y = (unsigned)f2bf(v0.z * inv) | ((unsigned)f2bf(v0.w * inv) << 16);
    st.z = (unsigned)f2bf(v1.x * inv) | ((unsigned)f2bf(v1.y * inv) << 16);
    st.w = (unsigned)f2bf(v1.z * inv) | ((unsigned)f2bf(v1.w * inv) << 16);
    *(uint4*)(out + lane * 8) = st;
}

// ---- pos[b] = 2 * dot(emb[b],pro[c]) / (|emb[b]| |pro[c]|), pure fp32. ----
__global__ void pos_kernel(const float* __restrict__ emb, const float* __restrict__ pro,
                           const int* __restrict__ cid, float* __restrict__ rowpos) {
    int b = blockIdx.x * 4 + (threadIdx.x >> 6);
    int lane = threadIdx.x & 63;
    int c = cid[b];
    const float4* ep = (const float4*)(emb + (size_t)b * D_N + lane * 8);
    const float4* pp = (const float4*)(pro + (size_t)c * D_N + lane * 8);
    float4 e0 = ep[0], e1 = ep[1], p0 = pp[0], p1 = pp[1];
    float dp = e0.x * p0.x + e0.y * p0.y + e0.z * p0.z + e0.w * p0.w +
               e1.x * p1.x + e1.y * p1.y + e1.z * p1.z + e1.w * p1.w;
    float ee = e0.x * e0.x + e0.y * e0.y + e0.z * e0.z + e0.w * e0.w +
               e1.x * e1.x + e1.y * e1.y + e1.z * e1.z + e1.w * e1.w;
    float qq = p0.x * p0.x + p0.y * p0.y + p0.z * p0.z + p0.w * p0.w +
               p1.x * p1.x + p1.y * p1.y + p1.z * p1.z + p1.w * p1.w;
    #pragma unroll
    for (int o = 32; o; o >>= 1) {
        dp += __shfl_xor(dp, o);
        ee += __shfl_xor(ee, o);
        qq += __shfl_xor(qq, o);
    }
    if (lane == 0)
        rowpos[b] = INV_T * dp / (fmaxf(sqrtf(ee), 1e-12f) * fmaxf(sqrtf(qq), 1e-12f));
}

// ---- flash GEMM: rowsum[b] += sum_k exp(2*dot(emb_n[b], proto_n[k])) ----
__global__ __launch_bounds__(256, 4) void flash_kernel(const unsigned short* __restrict__ embn,
                                                       const unsigned short* __restrict__ pron,
                                                       float* __restrict__ rowsum_g) {
    __shared__ __align__(16) unsigned short As[BM * BK];
    __shared__ __align__(16) unsigned short Bs[BN * BK];
    const int t = threadIdx.x;
    const int w = t >> 6, lane = t & 63;
    const int quad = lane >> 4, lcol = lane & 15;
    const int wm = w >> 1, wn = w & 1;
    const int rowBase = blockIdx.x * BM;
    const int nBegin = blockIdx.y * (K_N / SPLIT);

    float rowsum[16];
    #pragma unroll
    for (int i = 0; i < 16; i++) rowsum[i] = 0.0f;

    for (int nt0 = 0; nt0 < K_N / SPLIT; nt0 += BN) {
        const int nBase = nBegin + nt0;
        floatx4 acc[4][4];
        #pragma unroll
        for (int mt = 0; mt < 4; mt++)
            #pragma unroll
            for (int nt = 0; nt < 4; nt++) {
                floatx4 z = {0.0f, 0.0f, 0.0f, 0.0f};
                acc[mt][nt] = z;
            }
        for (int d0 = 0; d0 < D_N; d0 += BK) {
            // stage A (128x32) and B (128x32); global source chunk XOR-swizzled so
            // fragment reads hit all 8 LDS 16B bank-groups per 8-lane batch.
            #pragma unroll
            for (int p = 0; p < 2; p++) {
                int flat = p * 256 + t;
                int r = flat >> 2;
                int c16 = (flat & 3) ^ ((r >> 1) & 3);
                gl_lds16(embn + (size_t)(rowBase + r) * D_N + d0 + c16 * 8,
                         &As[(p * 256 + w * 64) * 8]);
                gl_lds16(pron + (size_t)(nBase + r) * D_N + d0 + c16 * 8,
                         &Bs[(p * 256 + w * 64) * 8]);
            }
            __syncthreads();
            short8 af[4], bf[4];
            #pragma unroll
            for (int mt = 0; mt < 4; mt++) {
                int row = wm * 64 + mt * 16 + lcol;
                af[mt] = *(const short8*)&As[row * BK + ((quad ^ ((row >> 1) & 3)) << 3)];
            }
            #pragma unroll
            for (int nt = 0; nt < 4; nt++) {
                int row = wn * 64 + nt * 16 + lcol;
                bf[nt] = *(const short8*)&Bs[row * BK + ((quad ^ ((row >> 1) & 3)) << 3)];
            }
            #pragma unroll
            for (int mt = 0; mt < 4; mt++)
                #pragma unroll
                for (int nt = 0; nt < 4; nt++)
                    acc[mt][nt] = __builtin_amdgcn_mfma_f32_16x16x32_bf16(af[mt], bf[nt],
                                                                          acc[mt][nt], 0, 0, 0);
            __syncthreads();
        }
        // epilogue: C/D layout col=lane&15, row=quad*4+reg
        #pragma unroll
        for (int mt = 0; mt < 4; mt++)
            #pragma unroll
            for (int nt = 0; nt < 4; nt++)
                #pragma unroll
                for (int r = 0; r < 4; r++)
                    rowsum[mt * 4 + r] += exp2f(acc[mt][nt][r] * LOG2E_X2);
    }
    #pragma unroll
    for (int i = 0; i < 16; i++) {
        #pragma unroll
        for (int o = 1; o < 16; o <<= 1) rowsum[i] += __shfl_xor(rowsum[i], o);
    }
    if (lcol == 0) {
        #pragma unroll
        for (int mt = 0; mt < 4; mt++)
            #pragma unroll
            for (int r = 0; r < 4; r++)
                atomicAdd(&rowsum_g[rowBase + wm * 64 + mt * 16 + quad * 4 + r],
                          rowsum[mt * 4 + r]);
    }
}

// ---- loss partial: 32 blocks, atomicAdd into out[0] (pre-zeroed). ----
__global__ void loss_kernel(const float* __restrict__ rowsum, const float* __restrict__ rowpos,
                            float* __restrict__ out) {
    __shared__ float red[256];
    int t = threadIdx.x;
    int b = blockIdx.x * 256 + t;
    float p = rowpos[b];
    red[t] = logf(rowsum[b] - __expf(p)) - p;
    __syncthreads();
    for (int o = 128; o; o >>= 1) {
        if (t < o) red[t] += red[t + o];
        __syncthreads();
    }
    if (t == 0) atomicAdd(out, red[0] * (1.0f / (float)B_N));
}

// ---- EMA phase 1: bucket occurrence indices per cluster. ----
__global__ void ema_count(const int* __restrict__ cid, int* __restrict__ cnt,
                          int* __restrict__ bucket) {
    int b = blockIdx.x * 256 + threadIdx.x;
    int c = cid[b];
    int slot = atomicAdd(&cnt[c], 1);
    if (slot < CAP) bucket[c * CAP + slot] = b;
}

// ---- EMA phase 2: one wave per cluster, replay occurrences in ascending b. ----
__global__ void ema_apply(const float* __restrict__ emb, const float* __restrict__ pro,
                          const int* __restrict__ cnt, const int* __restrict__ bucket,
                          float* __restrict__ outp) {
    int k = blockIdx.x * 4 + (threadIdx.x >> 6);
    int lane = threadIdx.x & 63;
    int n = cnt[k];
    n = n < CAP ? n : CAP;
    float a[8];
    #pragma unroll
    for (int j = 0; j < 8; j++) a[j] = pro[(size_t)k * D_N + j * 64 + lane];
    int myb = (lane < n) ? bucket[k * CAP + lane] : 0x7fffffff;
    for (int i = 0; i < n; i++) {
        int m = myb;
        #pragma unroll
        for (int o = 1; o < 64; o <<= 1) {
            int v = __shfl_xor(m, o);
            m = v < m ? v : m;
        }
        const float* e = emb + (size_t)m * D_N;
        #pragma unroll
        for (int j = 0; j < 8; j++) a[j] = MOM * a[j] + (1.0f - MOM) * e[j * 64 + lane];
        if (myb == m) myb = 0x7fffffff;
    }
    #pragma unroll
    for (int j = 0; j < 8; j++) outp[(size_t)k * D_N + j * 64 + lane] = a[j];
}

extern "C" void kernel_launch(void* const* d_in, const int* in_sizes, int n_in,
                              void* d_out, int out_size, void* d_ws, size_t ws_size,
                              hipStream_t stream) {
    const float* emb = (const float*)d_in[0];
    const int* cid = (const int*)d_in[1];
    const float* pro = (const float*)d_in[2];
    float* out = (float*)d_out;

    char* ws = (char*)d_ws;
    unsigned short* embn = (unsigned short*)ws;                    // 8 MB bf16 [B,D]
    unsigned short* pron = (unsigned short*)(ws + 8388608);        // 16 MB bf16 [K,D]
    float* rowsum = (float*)(ws + 25165824);                       // [B]
    float* rowpos = (float*)(ws + 25198592);                       // [B]
    // EMA buckets alias the pron region — only touched after flash_kernel (stream order).
    int* cnt = (int*)(ws + 8388608);                               // [K]
    int* bucket = (int*)(ws + 8388608 + 65536);                    // [K, CAP]

    hipMemsetAsync(rowsum, 0, B_N * sizeof(float), stream);
    hipMemsetAsync(out, 0, sizeof(float), stream);
    norm_kernel<<<(B_N + K_N) / 4, 256, 0, stream>>>(emb, pro, embn, pron);
    pos_kernel<<<B_N / 4, 256, 0, stream>>>(emb, pro, cid, rowpos);
    flash_kernel<<<dim3(B_N / BM, SPLIT), 256, 0, stream>>>(embn, pron, rowsum);
    loss_kernel<<<B_N / 256, 256, 0, stream>>>(rowsum, rowpos, out);
    // EMA (aliases pron region; safe: enqueued after flash on the same stream)
    hipMemsetAsync(cnt, 0, K_N * sizeof(int), stream);
    ema_count<<<B_N / 256, 256, 0, stream>>>(cid, cnt, bucket);
    ema_apply<<<K_N / 4, 256, 0, stream>>>(emb, pro, cnt, bucket, out + 1);
}

// Round 3
// 334.332 us; speedup vs baseline: 1.1590x; 1.1376x over previous
//
#include <hip/hip_runtime.h>
#include <hip/hip_bf16.h>

// PrototypeConsistentLearning: loss = mean(-pos + lse_neg), new_protos = serial EMA.
// B=8192, D=512, K=16384, T=0.5, momentum=0.9.
// R3: revert R2's __launch_bounds__(256,4) — it forced 64 arch VGPRs and spilled
// (FETCH 425MB / WRITE 160MB of scratch traffic). Keep SPLIT=16 (grid 1024) and
// the XOR swizzle (bank conflicts 1.68e7 -> 0).

#define B_N 8192
#define D_N 512
#define K_N 16384
#define INV_T 2.0f
#define MOM 0.9f
#define LOG2E_X2 2.8853900817779268f  // 2 * log2(e): exp(2a) = exp2(a * this)

#define BM 128
#define BN 128
#define BK 32
#define SPLIT 16
#define CAP 64

typedef __attribute__((ext_vector_type(8))) short short8;
typedef __attribute__((ext_vector_type(4))) float floatx4;

__device__ __forceinline__ unsigned short f2bf(float f) {
    unsigned int u = __float_as_uint(f);
    u += 0x7fffu + ((u >> 16) & 1u);
    return (unsigned short)(u >> 16);
}

__device__ __forceinline__ void gl_lds16(const void* g, void* lds) {
    __builtin_amdgcn_global_load_lds(
        (const __attribute__((address_space(1))) void*)g,
        (__attribute__((address_space(3))) void*)lds, 16, 0, 0);
}

// ---- normalize rows of emb and pro (fp32) -> bf16. one wave per row. ----
__global__ void norm_kernel(const float* __restrict__ emb, const float* __restrict__ pro,
                            unsigned short* __restrict__ embn, unsigned short* __restrict__ pron) {
    int row = blockIdx.x * 4 + (threadIdx.x >> 6);
    int lane = threadIdx.x & 63;
    const float* x;
    unsigned short* out;
    if (row < B_N) {
        x = emb + (size_t)row * D_N;
        out = embn + (size_t)row * D_N;
    } else {
        x = pro + (size_t)(row - B_N) * D_N;
        out = pron + (size_t)(row - B_N) * D_N;
    }
    const float4* xp = (const float4*)(x + lane * 8);
    float4 v0 = xp[0];
    float4 v1 = xp[1];
    float ss = v0.x * v0.x + v0.y * v0.y + v0.z * v0.z + v0.w * v0.w +
               v1.x * v1.x + v1.y * v1.y + v1.z * v1.z + v1.w * v1.w;
    #pragma unroll
    for (int o = 32; o; o >>= 1) ss += __shfl_xor(ss, o);
    float inv = 1.0f / fmaxf(sqrtf(ss), 1e-12f);
    uint4 st;
    st.x = (unsigned)f2bf(v0.x * inv) | ((unsigned)f2bf(v0.y * inv) << 16);
    st.y = (unsigned)f2bf(v0.z * inv) | ((unsigned)f2bf(v0.w * inv) << 16);
    st.z = (unsigned)f2bf(v1.x * inv) | ((unsigned)f2bf(v1.y * inv) << 16);
    st.w = (unsigned)f2bf(v1.z * inv) | ((unsigned)f2bf(v1.w * inv) << 16);
    *(uint4*)(out + lane * 8) = st;
}

// ---- pos[b] = 2 * dot(emb[b],pro[c]) / (|emb[b]| |pro[c]|), pure fp32. ----
__global__ void pos_kernel(const float* __restrict__ emb, const float* __restrict__ pro,
                           const int* __restrict__ cid, float* __restrict__ rowpos) {
    int b = blockIdx.x * 4 + (threadIdx.x >> 6);
    int lane = threadIdx.x & 63;
    int c = cid[b];
    const float4* ep = (const float4*)(emb + (size_t)b * D_N + lane * 8);
    const float4* pp = (const float4*)(pro + (size_t)c * D_N + lane * 8);
    float4 e0 = ep[0], e1 = ep[1], p0 = pp[0], p1 = pp[1];
    float dp = e0.x * p0.x + e0.y * p0.y + e0.z * p0.z + e0.w * p0.w +
               e1.x * p1.x + e1.y * p1.y + e1.z * p1.z + e1.w * p1.w;
    float ee = e0.x * e0.x + e0.y * e0.y + e0.z * e0.z + e0.w * e0.w +
               e1.x * e1.x + e1.y * e1.y + e1.z * e1.z + e1.w * e1.w;
    float qq = p0.x * p0.x + p0.y * p0.y + p0.z * p0.z + p0.w * p0.w +
               p1.x * p1.x + p1.y * p1.y + p1.z * p1.z + p1.w * p1.w;
    #pragma unroll
    for (int o = 32; o; o >>= 1) {
        dp += __shfl_xor(dp, o);
        ee += __shfl_xor(ee, o);
        qq += __shfl_xor(qq, o);
    }
    if (lane == 0)
        rowpos[b] = INV_T * dp / (fmaxf(sqrtf(ee), 1e-12f) * fmaxf(sqrtf(qq), 1e-12f));
}

// ---- flash GEMM: rowsum[b] += sum_k exp(2*dot(emb_n[b], proto_n[k])) ----
__global__ __launch_bounds__(256) void flash_kernel(const unsigned short* __restrict__ embn,
                                                    const unsigned short* __restrict__ pron,
                                                    float* __restrict__ rowsum_g) {
    __shared__ __align__(16) unsigned short As[BM * BK];
    __shared__ __align__(16) unsigned short Bs[BN * BK];
    const int t = threadIdx.x;
    const int w = t >> 6, lane = t & 63;
    const int quad = lane >> 4, lcol = lane & 15;
    const int wm = w >> 1, wn = w & 1;
    const int rowBase = blockIdx.x * BM;
    const int nBegin = blockIdx.y * (K_N / SPLIT);

    float rowsum[16];
    #pragma unroll
    for (int i = 0; i < 16; i++) rowsum[i] = 0.0f;

    for (int nt0 = 0; nt0 < K_N / SPLIT; nt0 += BN) {
        const int nBase = nBegin + nt0;
        floatx4 acc[4][4];
        #pragma unroll
        for (int mt = 0; mt < 4; mt++)
            #pragma unroll
            for (int nt = 0; nt < 4; nt++) {
                floatx4 z = {0.0f, 0.0f, 0.0f, 0.0f};
                acc[mt][nt] = z;
            }
        for (int d0 = 0; d0 < D_N; d0 += BK) {
            // stage A (128x32) and B (128x32); global source chunk XOR-swizzled so
            // fragment reads hit all 8 LDS 16B bank-groups per 8-lane batch.
            #pragma unroll
            for (int p = 0; p < 2; p++) {
                int flat = p * 256 + t;
                int r = flat >> 2;
                int c16 = (flat & 3) ^ ((r >> 1) & 3);
                gl_lds16(embn + (size_t)(rowBase + r) * D_N + d0 + c16 * 8,
                         &As[(p * 256 + w * 64) * 8]);
                gl_lds16(pron + (size_t)(nBase + r) * D_N + d0 + c16 * 8,
                         &Bs[(p * 256 + w * 64) * 8]);
            }
            __syncthreads();
            short8 af[4], bf[4];
            #pragma unroll
            for (int mt = 0; mt < 4; mt++) {
                int row = wm * 64 + mt * 16 + lcol;
                af[mt] = *(const short8*)&As[row * BK + ((quad ^ ((row >> 1) & 3)) << 3)];
            }
            #pragma unroll
            for (int nt = 0; nt < 4; nt++) {
                int row = wn * 64 + nt * 16 + lcol;
                bf[nt] = *(const short8*)&Bs[row * BK + ((quad ^ ((row >> 1) & 3)) << 3)];
            }
            #pragma unroll
            for (int mt = 0; mt < 4; mt++)
                #pragma unroll
                for (int nt = 0; nt < 4; nt++)
                    acc[mt][nt] = __builtin_amdgcn_mfma_f32_16x16x32_bf16(af[mt], bf[nt],
                                                                          acc[mt][nt], 0, 0, 0);
            __syncthreads();
        }
        // epilogue: C/D layout col=lane&15, row=quad*4+reg
        #pragma unroll
        for (int mt = 0; mt < 4; mt++)
            #pragma unroll
            for (int nt = 0; nt < 4; nt++)
                #pragma unroll
                for (int r = 0; r < 4; r++)
                    rowsum[mt * 4 + r] += exp2f(acc[mt][nt][r] * LOG2E_X2);
    }
    #pragma unroll
    for (int i = 0; i < 16; i++) {
        #pragma unroll
        for (int o = 1; o < 16; o <<= 1) rowsum[i] += __shfl_xor(rowsum[i], o);
    }
    if (lcol == 0) {
        #pragma unroll
        for (int mt = 0; mt < 4; mt++)
            #pragma unroll
            for (int r = 0; r < 4; r++)
                atomicAdd(&rowsum_g[rowBase + wm * 64 + mt * 16 + quad * 4 + r],
                          rowsum[mt * 4 + r]);
    }
}

// ---- loss partial: 32 blocks, atomicAdd into out[0] (pre-zeroed). ----
__global__ void loss_kernel(const float* __restrict__ rowsum, const float* __restrict__ rowpos,
                            float* __restrict__ out) {
    __shared__ float red[256];
    int t = threadIdx.x;
    int b = blockIdx.x * 256 + t;
    float p = rowpos[b];
    red[t] = logf(rowsum[b] - __expf(p)) - p;
    __syncthreads();
    for (int o = 128; o; o >>= 1) {
        if (t < o) red[t] += red[t + o];
        __syncthreads();
    }
    if (t == 0) atomicAdd(out, red[0] * (1.0f / (float)B_N));
}

// ---- EMA phase 1: bucket occurrence indices per cluster. ----
__global__ void ema_count(const int* __restrict__ cid, int* __restrict__ cnt,
                          int* __restrict__ bucket) {
    int b = blockIdx.x * 256 + threadIdx.x;
    int c = cid[b];
    int slot = atomicAdd(&cnt[c], 1);
    if (slot < CAP) bucket[c * CAP + slot] = b;
}

// ---- EMA phase 2: one wave per cluster, replay occurrences in ascending b. ----
__global__ void ema_apply(const float* __restrict__ emb, const float* __restrict__ pro,
                          const int* __restrict__ cnt, const int* __restrict__ bucket,
                          float* __restrict__ outp) {
    int k = blockIdx.x * 4 + (threadIdx.x >> 6);
    int lane = threadIdx.x & 63;
    int n = cnt[k];
    n = n < CAP ? n : CAP;
    float a[8];
    #pragma unroll
    for (int j = 0; j < 8; j++) a[j] = pro[(size_t)k * D_N + j * 64 + lane];
    int myb = (lane < n) ? bucket[k * CAP + lane] : 0x7fffffff;
    for (int i = 0; i < n; i++) {
        int m = myb;
        #pragma unroll
        for (int o = 1; o < 64; o <<= 1) {
            int v = __shfl_xor(m, o);
            m = v < m ? v : m;
        }
        const float* e = emb + (size_t)m * D_N;
        #pragma unroll
        for (int j = 0; j < 8; j++) a[j] = MOM * a[j] + (1.0f - MOM) * e[j * 64 + lane];
        if (myb == m) myb = 0x7fffffff;
    }
    #pragma unroll
    for (int j = 0; j < 8; j++) outp[(size_t)k * D_N + j * 64 + lane] = a[j];
}

extern "C" void kernel_launch(void* const* d_in, const int* in_sizes, int n_in,
                              void* d_out, int out_size, void* d_ws, size_t ws_size,
                              hipStream_t stream) {
    const float* emb = (const float*)d_in[0];
    const int* cid = (const int*)d_in[1];
    const float* pro = (const float*)d_in[2];
    float* out = (float*)d_out;

    char* ws = (char*)d_ws;
    unsigned short* embn = (unsigned short*)ws;                    // 8 MB bf16 [B,D]
    unsigned short* pron = (unsigned short*)(ws + 8388608);        // 16 MB bf16 [K,D]
    float* rowsum = (float*)(ws + 25165824);                       // [B]
    float* rowpos = (float*)(ws + 25198592);                       // [B]
    // EMA buckets alias the pron region — only touched after flash_kernel (stream order).
    int* cnt = (int*)(ws + 8388608);                               // [K]
    int* bucket = (int*)(ws + 8388608 + 65536);                    // [K, CAP]

    hipMemsetAsync(rowsum, 0, B_N * sizeof(float), stream);
    hipMemsetAsync(out, 0, sizeof(float), stream);
    norm_kernel<<<(B_N + K_N) / 4, 256, 0, stream>>>(emb, pro, embn, pron);
    pos_kernel<<<B_N / 4, 256, 0, stream>>>(emb, pro, cid, rowpos);
    flash_kernel<<<dim3(B_N / BM, SPLIT), 256, 0, stream>>>(embn, pron, rowsum);
    loss_kernel<<<B_N / 256, 256, 0, stream>>>(rowsum, rowpos, out);
    // EMA (aliases pron region; safe: enqueued after flash on the same stream)
    hipMemsetAsync(cnt, 0, K_N * sizeof(int), stream);
    ema_count<<<B_N / 256, 256, 0, stream>>>(cid, cnt, bucket);
    ema_apply<<<K_N / 4, 256, 0, stream>>>(emb, pro, cnt, bucket, out + 1);
}

// Round 4
// 334.311 us; speedup vs baseline: 1.1591x; 1.0001x over previous
//
#include <hip/hip_runtime.h>
#include <hip/hip_bf16.h>

// PrototypeConsistentLearning: loss = mean(-pos + lse_neg), new_protos = serial EMA.
// B=8192, D=512, K=16384, T=0.5, momentum=0.9.
// R4: occupancy model = floor(512/(arch+acc)) per SIMD. R3 was 112+64=176 -> 2 waves/SIMD.
// __launch_bounds__(256,3) caps total ~170 (arch<=104) -> 3 waves/SIMD; LDS frag addrs
// hoisted (swizzle is mt-invariant: bits 1-2 of row come only from lcol). SPLIT=32 for
// load balance at 3 blocks/CU. __expf (native v_exp) instead of exp2f (libm fixups,
// VALUBusy 40->45 in R3). Tail: 11 dispatches -> 6 (zeroing folded into norm/loss).

#define B_N 8192
#define D_N 512
#define K_N 16384
#define INV_T 2.0f
#define MOM 0.9f

#define BM 128
#define BN 128
#define BK 32
#define SPLIT 32
#define CAP 64

typedef __attribute__((ext_vector_type(8))) short short8;
typedef __attribute__((ext_vector_type(4))) float floatx4;

__device__ __forceinline__ unsigned short f2bf(float f) {
    unsigned int u = __float_as_uint(f);
    u += 0x7fffu + ((u >> 16) & 1u);
    return (unsigned short)(u >> 16);
}

__device__ __forceinline__ void gl_lds16(const void* g, void* lds) {
    __builtin_amdgcn_global_load_lds(
        (const __attribute__((address_space(1))) void*)g,
        (__attribute__((address_space(3))) void*)lds, 16, 0, 0);
}

// ---- normalize rows of emb and pro (fp32) -> bf16; also zero rowsum and out[0]. ----
__global__ void norm_kernel(const float* __restrict__ emb, const float* __restrict__ pro,
                            unsigned short* __restrict__ embn, unsigned short* __restrict__ pron,
                            float* __restrict__ rowsum, float* __restrict__ out) {
    if (blockIdx.x < 32) rowsum[blockIdx.x * 256 + threadIdx.x] = 0.0f;
    if (blockIdx.x == 32 && threadIdx.x == 0) out[0] = 0.0f;
    int row = blockIdx.x * 4 + (threadIdx.x >> 6);
    int lane = threadIdx.x & 63;
    const float* x;
    unsigned short* o;
    if (row < B_N) {
        x = emb + (size_t)row * D_N;
        o = embn + (size_t)row * D_N;
    } else {
        x = pro + (size_t)(row - B_N) * D_N;
        o = pron + (size_t)(row - B_N) * D_N;
    }
    const float4* xp = (const float4*)(x + lane * 8);
    float4 v0 = xp[0];
    float4 v1 = xp[1];
    float ss = v0.x * v0.x + v0.y * v0.y + v0.z * v0.z + v0.w * v0.w +
               v1.x * v1.x + v1.y * v1.y + v1.z * v1.z + v1.w * v1.w;
    #pragma unroll
    for (int of = 32; of; of >>= 1) ss += __shfl_xor(ss, of);
    float inv = 1.0f / fmaxf(sqrtf(ss), 1e-12f);
    uint4 st;
    st.x = (unsigned)f2bf(v0.x * inv) | ((unsigned)f2bf(v0.y * inv) << 16);
    st.y = (unsigned)f2bf(v0.z * inv) | ((unsigned)f2bf(v0.w * inv) << 16);
    st.z = (unsigned)f2bf(v1.x * inv) | ((unsigned)f2bf(v1.y * inv) << 16);
    st.w = (unsigned)f2bf(v1.z * inv) | ((unsigned)f2bf(v1.w * inv) << 16);
    *(uint4*)(o + lane * 8) = st;
}

// ---- pos[b] = 2 * dot(emb[b],pro[c]) / (|emb[b]| |pro[c]|), pure fp32. ----
__global__ void pos_kernel(const float* __restrict__ emb, const float* __restrict__ pro,
                           const int* __restrict__ cid, float* __restrict__ rowpos) {
    int b = blockIdx.x * 4 + (threadIdx.x >> 6);
    int lane = threadIdx.x & 63;
    int c = cid[b];
    const float4* ep = (const float4*)(emb + (size_t)b * D_N + lane * 8);
    const float4* pp = (const float4*)(pro + (size_t)c * D_N + lane * 8);
    float4 e0 = ep[0], e1 = ep[1], p0 = pp[0], p1 = pp[1];
    float dp = e0.x * p0.x + e0.y * p0.y + e0.z * p0.z + e0.w * p0.w +
               e1.x * p1.x + e1.y * p1.y + e1.z * p1.z + e1.w * p1.w;
    float ee = e0.x * e0.x + e0.y * e0.y + e0.z * e0.z + e0.w * e0.w +
               e1.x * e1.x + e1.y * e1.y + e1.z * e1.z + e1.w * e1.w;
    float qq = p0.x * p0.x + p0.y * p0.y + p0.z * p0.z + p0.w * p0.w +
               p1.x * p1.x + p1.y * p1.y + p1.z * p1.z + p1.w * p1.w;
    #pragma unroll
    for (int o = 32; o; o >>= 1) {
        dp += __shfl_xor(dp, o);
        ee += __shfl_xor(ee, o);
        qq += __shfl_xor(qq, o);
    }
    if (lane == 0)
        rowpos[b] = INV_T * dp / (fmaxf(sqrtf(ee), 1e-12f) * fmaxf(sqrtf(qq), 1e-12f));
}

// ---- flash GEMM: rowsum[b] += sum_k exp(2*dot(emb_n[b], proto_n[k])) ----
__global__ __launch_bounds__(256, 3) void flash_kernel(const unsigned short* __restrict__ embn,
                                                       const unsigned short* __restrict__ pron,
                                                       float* __restrict__ rowsum_g) {
    __shared__ __align__(16) unsigned short As[BM * BK];
    __shared__ __align__(16) unsigned short Bs[BN * BK];
    const int t = threadIdx.x;
    const int w = t >> 6, lane = t & 63;
    const int quad = lane >> 4, lcol = lane & 15;
    const int wm = w >> 1, wn = w & 1;
    const int rowBase = blockIdx.x * BM;
    const int nBegin = blockIdx.y * (K_N / SPLIT);

    // Loop-invariant LDS fragment offsets: swizzle bits depend only on lcol bits 1-2
    // (wm*64 and mt*16 don't touch bits 1-2 of row), so mt/nt vary via imm offsets.
    const int swz = (quad ^ ((lcol >> 1) & 3)) << 3;
    const int aOff = (wm * 64 + lcol) * BK + swz;
    const int bOff = (wn * 64 + lcol) * BK + swz;
    // Staging source (lane-invariant parts): flat index -> row, swizzled chunk.
    const int r0 = t >> 2, r1 = (256 + t) >> 2;
    const int c0 = ((t & 3) ^ ((r0 >> 1) & 3)) * 8;
    const int c1 = ((t & 3) ^ ((r1 >> 1) & 3)) * 8;

    float rowsum[16];
    #pragma unroll
    for (int i = 0; i < 16; i++) rowsum[i] = 0.0f;

    for (int nt0 = 0; nt0 < K_N / SPLIT; nt0 += BN) {
        const int nBase = nBegin + nt0;
        floatx4 acc[4][4];
        #pragma unroll
        for (int mt = 0; mt < 4; mt++)
            #pragma unroll
            for (int nt = 0; nt < 4; nt++) {
                floatx4 z = {0.0f, 0.0f, 0.0f, 0.0f};
                acc[mt][nt] = z;
            }
        const unsigned short* aSrc0 = embn + (size_t)(rowBase + r0) * D_N + c0;
        const unsigned short* aSrc1 = embn + (size_t)(rowBase + r1) * D_N + c1;
        const unsigned short* bSrc0 = pron + (size_t)(nBase + r0) * D_N + c0;
        const unsigned short* bSrc1 = pron + (size_t)(nBase + r1) * D_N + c1;
        for (int d0 = 0; d0 < D_N; d0 += BK) {
            gl_lds16(aSrc0 + d0, &As[(w * 64) * 8]);
            gl_lds16(aSrc1 + d0, &As[(256 + w * 64) * 8]);
            gl_lds16(bSrc0 + d0, &Bs[(w * 64) * 8]);
            gl_lds16(bSrc1 + d0, &Bs[(256 + w * 64) * 8]);
            __syncthreads();
            short8 af[4], bf[4];
            #pragma unroll
            for (int mt = 0; mt < 4; mt++)
                af[mt] = *(const short8*)&As[aOff + mt * 16 * BK];
            #pragma unroll
            for (int nt = 0; nt < 4; nt++)
                bf[nt] = *(const short8*)&Bs[bOff + nt * 16 * BK];
            #pragma unroll
            for (int mt = 0; mt < 4; mt++)
                #pragma unroll
                for (int nt = 0; nt < 4; nt++)
                    acc[mt][nt] = __builtin_amdgcn_mfma_f32_16x16x32_bf16(af[mt], bf[nt],
                                                                          acc[mt][nt], 0, 0, 0);
            __syncthreads();
        }
        // epilogue: C/D layout col=lane&15, row=quad*4+reg
        #pragma unroll
        for (int mt = 0; mt < 4; mt++)
            #pragma unroll
            for (int nt = 0; nt < 4; nt++)
                #pragma unroll
                for (int r = 0; r < 4; r++)
                    rowsum[mt * 4 + r] += __expf(acc[mt][nt][r] * INV_T);
    }
    #pragma unroll
    for (int i = 0; i < 16; i++) {
        #pragma unroll
        for (int o = 1; o < 16; o <<= 1) rowsum[i] += __shfl_xor(rowsum[i], o);
    }
    if (lcol == 0) {
        #pragma unroll
        for (int mt = 0; mt < 4; mt++)
            #pragma unroll
            for (int r = 0; r < 4; r++)
                atomicAdd(&rowsum_g[rowBase + wm * 64 + mt * 16 + quad * 4 + r],
                          rowsum[mt * 4 + r]);
    }
}

// ---- loss partial: 32 blocks, atomicAdd into out[0]; also zero cnt for EMA. ----
__global__ void loss_kernel(const float* __restrict__ rowsum, const float* __restrict__ rowpos,
                            float* __restrict__ out, int* __restrict__ cnt) {
    __shared__ float red[256];
    int t = threadIdx.x;
    int b = blockIdx.x * 256 + t;
    cnt[b * 2] = 0;
    cnt[b * 2 + 1] = 0;
    float p = rowpos[b];
    red[t] = logf(rowsum[b] - __expf(p)) - p;
    __syncthreads();
    for (int o = 128; o; o >>= 1) {
        if (t < o) red[t] += red[t + o];
        __syncthreads();
    }
    if (t == 0) atomicAdd(out, red[0] * (1.0f / (float)B_N));
}

// ---- EMA phase 1: bucket occurrence indices per cluster. ----
__global__ void ema_count(const int* __restrict__ cid, int* __restrict__ cnt,
                          int* __restrict__ bucket) {
    int b = blockIdx.x * 256 + threadIdx.x;
    int c = cid[b];
    int slot = atomicAdd(&cnt[c], 1);
    if (slot < CAP) bucket[c * CAP + slot] = b;
}

// ---- EMA phase 2: one wave per cluster, replay occurrences in ascending b. ----
__global__ void ema_apply(const float* __restrict__ emb, const float* __restrict__ pro,
                          const int* __restrict__ cnt, const int* __restrict__ bucket,
                          float* __restrict__ outp) {
    int k = blockIdx.x * 4 + (threadIdx.x >> 6);
    int lane = threadIdx.x & 63;
    int n = cnt[k];
    n = n < CAP ? n : CAP;
    const float4* pp = (const float4*)(pro + (size_t)k * D_N + lane * 8);
    float4 a0 = pp[0], a1 = pp[1];
    int myb = (lane < n) ? bucket[k * CAP + lane] : 0x7fffffff;
    for (int i = 0; i < n; i++) {
        int m = myb;
        #pragma unroll
        for (int o = 1; o < 64; o <<= 1) {
            int v = __shfl_xor(m, o);
            m = v < m ? v : m;
        }
        const float4* ep = (const float4*)(emb + (size_t)m * D_N + lane * 8);
        float4 e0 = ep[0], e1 = ep[1];
        a0.x = MOM * a0.x + (1.0f - MOM) * e0.x;
        a0.y = MOM * a0.y + (1.0f - MOM) * e0.y;
        a0.z = MOM * a0.z + (1.0f - MOM) * e0.z;
        a0.w = MOM * a0.w + (1.0f - MOM) * e0.w;
        a1.x = MOM * a1.x + (1.0f - MOM) * e1.x;
        a1.y = MOM * a1.y + (1.0f - MOM) * e1.y;
        a1.z = MOM * a1.z + (1.0f - MOM) * e1.z;
        a1.w = MOM * a1.w + (1.0f - MOM) * e1.w;
        if (myb == m) myb = 0x7fffffff;
    }
    float4* op = (float4*)(outp + (size_t)k * D_N + lane * 8);
    op[0] = a0;
    op[1] = a1;
}

extern "C" void kernel_launch(void* const* d_in, const int* in_sizes, int n_in,
                              void* d_out, int out_size, void* d_ws, size_t ws_size,
                              hipStream_t stream) {
    const float* emb = (const float*)d_in[0];
    const int* cid = (const int*)d_in[1];
    const float* pro = (const float*)d_in[2];
    float* out = (float*)d_out;

    char* ws = (char*)d_ws;
    unsigned short* embn = (unsigned short*)ws;                    // 8 MB bf16 [B,D]
    unsigned short* pron = (unsigned short*)(ws + 8388608);        // 16 MB bf16 [K,D]
    float* rowsum = (float*)(ws + 25165824);                       // [B]
    float* rowpos = (float*)(ws + 25198592);                       // [B]
    // EMA buckets alias the pron region — only touched after flash_kernel (stream order):
    // loss_kernel zeroes cnt, ema_count fills, ema_apply reads.
    int* cnt = (int*)(ws + 8388608);                               // [K]
    int* bucket = (int*)(ws + 8388608 + 65536);                    // [K, CAP]

    norm_kernel<<<(B_N + K_N) / 4, 256, 0, stream>>>(emb, pro, embn, pron, rowsum, out);
    pos_kernel<<<B_N / 4, 256, 0, stream>>>(emb, pro, cid, rowpos);
    flash_kernel<<<dim3(B_N / BM, SPLIT), 256, 0, stream>>>(embn, pron, rowsum);
    loss_kernel<<<B_N / 256, 256, 0, stream>>>(rowsum, rowpos, out, cnt);
    ema_count<<<B_N / 256, 256, 0, stream>>>(cid, cnt, bucket);
    ema_apply<<<K_N / 4, 256, 0, stream>>>(emb, pro, cnt, bucket, out + 1);
}

// Round 5
// 283.449 us; speedup vs baseline: 1.3670x; 1.1794x over previous
//
#include <hip/hip_runtime.h>
#include <hip/hip_bf16.h>

// PrototypeConsistentLearning: loss = mean(-pos + lse_neg), new_protos = serial EMA.
// B=8192, D=512, K=16384, T=0.5, momentum=0.9.
// R5: (a) fully unroll the D-loop so staging/ds_read offsets become instruction
// immediates (R3/R4 showed ~40 VALU addr-calc per 16 MFMA -> VALUBusy 45%);
// (b) pipeline: barrier -> ds_read -> barrier -> issue NEXT chunk gl_lds -> MFMA,
// so load latency overlaps MFMA instead of being serially exposed; tile-boundary
// chunk-0 loads overlap the exp epilogue. Plain __launch_bounds__(256): R2(,4) and
// R4(,3) both spilled (WRITE 160/80 MB) for zero net gain — this kernel wants
// ~112 arch + 64 acc regs = 2 waves/SIMD.

#define B_N 8192
#define D_N 512
#define K_N 16384
#define INV_T 2.0f
#define MOM 0.9f

#define BM 128
#define BN 128
#define BK 32
#define SPLIT 32
#define NITER (D_N / BK)   // 16
#define CAP 64

typedef __attribute__((ext_vector_type(8))) short short8;
typedef __attribute__((ext_vector_type(4))) float floatx4;

__device__ __forceinline__ unsigned short f2bf(float f) {
    unsigned int u = __float_as_uint(f);
    u += 0x7fffu + ((u >> 16) & 1u);
    return (unsigned short)(u >> 16);
}

__device__ __forceinline__ void gl_lds16(const void* g, void* lds) {
    __builtin_amdgcn_global_load_lds(
        (const __attribute__((address_space(1))) void*)g,
        (__attribute__((address_space(3))) void*)lds, 16, 0, 0);
}

// ---- normalize rows of emb and pro (fp32) -> bf16; also zero rowsum and out[0]. ----
__global__ void norm_kernel(const float* __restrict__ emb, const float* __restrict__ pro,
                            unsigned short* __restrict__ embn, unsigned short* __restrict__ pron,
                            float* __restrict__ rowsum, float* __restrict__ out) {
    if (blockIdx.x < 32) rowsum[blockIdx.x * 256 + threadIdx.x] = 0.0f;
    if (blockIdx.x == 32 && threadIdx.x == 0) out[0] = 0.0f;
    int row = blockIdx.x * 4 + (threadIdx.x >> 6);
    int lane = threadIdx.x & 63;
    const float* x;
    unsigned short* o;
    if (row < B_N) {
        x = emb + (size_t)row * D_N;
        o = embn + (size_t)row * D_N;
    } else {
        x = pro + (size_t)(row - B_N) * D_N;
        o = pron + (size_t)(row - B_N) * D_N;
    }
    const float4* xp = (const float4*)(x + lane * 8);
    float4 v0 = xp[0];
    float4 v1 = xp[1];
    float ss = v0.x * v0.x + v0.y * v0.y + v0.z * v0.z + v0.w * v0.w +
               v1.x * v1.x + v1.y * v1.y + v1.z * v1.z + v1.w * v1.w;
    #pragma unroll
    for (int of = 32; of; of >>= 1) ss += __shfl_xor(ss, of);
    float inv = 1.0f / fmaxf(sqrtf(ss), 1e-12f);
    uint4 st;
    st.x = (unsigned)f2bf(v0.x * inv) | ((unsigned)f2bf(v0.y * inv) << 16);
    st.y = (unsigned)f2bf(v0.z * inv) | ((unsigned)f2bf(v0.w * inv) << 16);
    st.z = (unsigned)f2bf(v1.x * inv) | ((unsigned)f2bf(v1.y * inv) << 16);
    st.w = (unsigned)f2bf(v1.z * inv) | ((unsigned)f2bf(v1.w * inv) << 16);
    *(uint4*)(o + lane * 8) = st;
}

// ---- pos[b] = 2 * dot(emb[b],pro[c]) / (|emb[b]| |pro[c]|), pure fp32. ----
__global__ void pos_kernel(const float* __restrict__ emb, const float* __restrict__ pro,
                           const int* __restrict__ cid, float* __restrict__ rowpos) {
    int b = blockIdx.x * 4 + (threadIdx.x >> 6);
    int lane = threadIdx.x & 63;
    int c = cid[b];
    const float4* ep = (const float4*)(emb + (size_t)b * D_N + lane * 8);
    const float4* pp = (const float4*)(pro + (size_t)c * D_N + lane * 8);
    float4 e0 = ep[0], e1 = ep[1], p0 = pp[0], p1 = pp[1];
    float dp = e0.x * p0.x + e0.y * p0.y + e0.z * p0.z + e0.w * p0.w +
               e1.x * p1.x + e1.y * p1.y + e1.z * p1.z + e1.w * p1.w;
    float ee = e0.x * e0.x + e0.y * e0.y + e0.z * e0.z + e0.w * e0.w +
               e1.x * e1.x + e1.y * e1.y + e1.z * e1.z + e1.w * e1.w;
    float qq = p0.x * p0.x + p0.y * p0.y + p0.z * p0.z + p0.w * p0.w +
               p1.x * p1.x + p1.y * p1.y + p1.z * p1.z + p1.w * p1.w;
    #pragma unroll
    for (int o = 32; o; o >>= 1) {
        dp += __shfl_xor(dp, o);
        ee += __shfl_xor(ee, o);
        qq += __shfl_xor(qq, o);
    }
    if (lane == 0)
        rowpos[b] = INV_T * dp / (fmaxf(sqrtf(ee), 1e-12f) * fmaxf(sqrtf(qq), 1e-12f));
}

// ---- flash GEMM: rowsum[b] += sum_k exp(2*dot(emb_n[b], proto_n[k])) ----
__global__ __launch_bounds__(256) void flash_kernel(const unsigned short* __restrict__ embn,
                                                    const unsigned short* __restrict__ pron,
                                                    float* __restrict__ rowsum_g) {
    __shared__ __align__(16) unsigned short As[BM * BK];
    __shared__ __align__(16) unsigned short Bs[BN * BK];
    const int t = threadIdx.x;
    const int w = t >> 6, lane = t & 63;
    const int quad = lane >> 4, lcol = lane & 15;
    const int wm = w >> 1, wn = w & 1;
    const int rowBase = blockIdx.x * BM;
    const int nBegin = blockIdx.y * (K_N / SPLIT);

    // Loop-invariant LDS fragment offsets (swizzle bits come only from lcol bits 1-2).
    const int swz = (quad ^ ((lcol >> 1) & 3)) << 3;
    unsigned short* aFrag = &As[(wm * 64 + lcol) * BK + swz];
    unsigned short* bFrag = &Bs[(wn * 64 + lcol) * BK + swz];
    // Staging: flat lane -> (row, swizzled 8-elem chunk); LDS dest wave-uniform.
    const int r0 = t >> 2, r1 = (256 + t) >> 2;
    const int c0 = ((t & 3) ^ ((r0 >> 1) & 3)) * 8;
    const int c1 = ((t & 3) ^ ((r1 >> 1) & 3)) * 8;
    unsigned short* aDst0 = &As[(w * 64) * 8];
    unsigned short* aDst1 = &As[(256 + w * 64) * 8];
    unsigned short* bDst0 = &Bs[(w * 64) * 8];
    unsigned short* bDst1 = &Bs[(256 + w * 64) * 8];
    const unsigned short* aSrc0 = embn + (size_t)(rowBase + r0) * D_N + c0;
    const unsigned short* aSrc1 = embn + (size_t)(rowBase + r1) * D_N + c1;

    float rowsum[16];
    #pragma unroll
    for (int i = 0; i < 16; i++) rowsum[i] = 0.0f;

    const unsigned short* bSrc0 = pron + (size_t)(nBegin + r0) * D_N + c0;
    const unsigned short* bSrc1 = pron + (size_t)(nBegin + r1) * D_N + c1;
    // issue chunk 0 of tile 0
    gl_lds16(aSrc0, aDst0);
    gl_lds16(aSrc1, aDst1);
    gl_lds16(bSrc0, bDst0);
    gl_lds16(bSrc1, bDst1);

    for (int tile = 0; tile < (K_N / SPLIT) / BN; tile++) {
        floatx4 acc[4][4];
        #pragma unroll
        for (int mt = 0; mt < 4; mt++)
            #pragma unroll
            for (int nt = 0; nt < 4; nt++) {
                floatx4 z = {0.0f, 0.0f, 0.0f, 0.0f};
                acc[mt][nt] = z;
            }
        #pragma unroll
        for (int it = 0; it < NITER; it++) {
            __syncthreads();  // staging of chunk `it` complete (vmcnt drained)
            short8 af[4], bf[4];
            #pragma unroll
            for (int mt = 0; mt < 4; mt++)
                af[mt] = *(const short8*)(aFrag + it * (BM * BK) / NITER * 0 + mt * 16 * BK);
            #pragma unroll
            for (int nt = 0; nt < 4; nt++)
                bf[nt] = *(const short8*)(bFrag + nt * 16 * BK);
            __syncthreads();  // all waves have frags in regs; LDS reusable
            if (it + 1 < NITER) {
                // prefetch chunk it+1 of this tile (constant byte offsets after unroll)
                gl_lds16(aSrc0 + (it + 1) * BK, aDst0);
                gl_lds16(aSrc1 + (it + 1) * BK, aDst1);
                gl_lds16(bSrc0 + (it + 1) * BK, bDst0);
                gl_lds16(bSrc1 + (it + 1) * BK, bDst1);
            } else if (tile + 1 < (K_N / SPLIT) / BN) {
                // prefetch chunk 0 of next tile; overlaps the exp epilogue below
                gl_lds16(aSrc0, aDst0);
                gl_lds16(aSrc1, aDst1);
                gl_lds16(bSrc0 + BN * D_N, bDst0);
                gl_lds16(bSrc1 + BN * D_N, bDst1);
            }
            #pragma unroll
            for (int mt = 0; mt < 4; mt++)
                #pragma unroll
                for (int nt = 0; nt < 4; nt++)
                    acc[mt][nt] = __builtin_amdgcn_mfma_f32_16x16x32_bf16(af[mt], bf[nt],
                                                                          acc[mt][nt], 0, 0, 0);
        }
        bSrc0 += BN * D_N;
        bSrc1 += BN * D_N;
        // epilogue: C/D layout col=lane&15, row=quad*4+reg
        #pragma unroll
        for (int mt = 0; mt < 4; mt++)
            #pragma unroll
            for (int nt = 0; nt < 4; nt++)
                #pragma unroll
                for (int r = 0; r < 4; r++)
                    rowsum[mt * 4 + r] += __expf(acc[mt][nt][r] * INV_T);
    }
    #pragma unroll
    for (int i = 0; i < 16; i++) {
        #pragma unroll
        for (int o = 1; o < 16; o <<= 1) rowsum[i] += __shfl_xor(rowsum[i], o);
    }
    if (lcol == 0) {
        #pragma unroll
        for (int mt = 0; mt < 4; mt++)
            #pragma unroll
            for (int r = 0; r < 4; r++)
                atomicAdd(&rowsum_g[rowBase + wm * 64 + mt * 16 + quad * 4 + r],
                          rowsum[mt * 4 + r]);
    }
}

// ---- loss partial: 32 blocks, atomicAdd into out[0]; also zero cnt for EMA. ----
__global__ void loss_kernel(const float* __restrict__ rowsum, const float* __restrict__ rowpos,
                            float* __restrict__ out, int* __restrict__ cnt) {
    __shared__ float red[256];
    int t = threadIdx.x;
    int b = blockIdx.x * 256 + t;
    cnt[b * 2] = 0;
    cnt[b * 2 + 1] = 0;
    float p = rowpos[b];
    red[t] = logf(rowsum[b] - __expf(p)) - p;
    __syncthreads();
    for (int o = 128; o; o >>= 1) {
        if (t < o) red[t] += red[t + o];
        __syncthreads();
    }
    if (t == 0) atomicAdd(out, red[0] * (1.0f / (float)B_N));
}

// ---- EMA phase 1: bucket occurrence indices per cluster. ----
__global__ void ema_count(const int* __restrict__ cid, int* __restrict__ cnt,
                          int* __restrict__ bucket) {
    int b = blockIdx.x * 256 + threadIdx.x;
    int c = cid[b];
    int slot = atomicAdd(&cnt[c], 1);
    if (slot < CAP) bucket[c * CAP + slot] = b;
}

// ---- EMA phase 2: one wave per cluster, replay occurrences in ascending b. ----
__global__ void ema_apply(const float* __restrict__ emb, const float* __restrict__ pro,
                          const int* __restrict__ cnt, const int* __restrict__ bucket,
                          float* __restrict__ outp) {
    int k = blockIdx.x * 4 + (threadIdx.x >> 6);
    int lane = threadIdx.x & 63;
    int n = cnt[k];
    n = n < CAP ? n : CAP;
    const float4* pp = (const float4*)(pro + (size_t)k * D_N + lane * 8);
    float4 a0 = pp[0], a1 = pp[1];
    int myb = (lane < n) ? bucket[k * CAP + lane] : 0x7fffffff;
    for (int i = 0; i < n; i++) {
        int m = myb;
        #pragma unroll
        for (int o = 1; o < 64; o <<= 1) {
            int v = __shfl_xor(m, o);
            m = v < m ? v : m;
        }
        const float4* ep = (const float4*)(emb + (size_t)m * D_N + lane * 8);
        float4 e0 = ep[0], e1 = ep[1];
        a0.x = MOM * a0.x + (1.0f - MOM) * e0.x;
        a0.y = MOM * a0.y + (1.0f - MOM) * e0.y;
        a0.z = MOM * a0.z + (1.0f - MOM) * e0.z;
        a0.w = MOM * a0.w + (1.0f - MOM) * e0.w;
        a1.x = MOM * a1.x + (1.0f - MOM) * e1.x;
        a1.y = MOM * a1.y + (1.0f - MOM) * e1.y;
        a1.z = MOM * a1.z + (1.0f - MOM) * e1.z;
        a1.w = MOM * a1.w + (1.0f - MOM) * e1.w;
        if (myb == m) myb = 0x7fffffff;
    }
    float4* op = (float4*)(outp + (size_t)k * D_N + lane * 8);
    op[0] = a0;
    op[1] = a1;
}

extern "C" void kernel_launch(void* const* d_in, const int* in_sizes, int n_in,
                              void* d_out, int out_size, void* d_ws, size_t ws_size,
                              hipStream_t stream) {
    const float* emb = (const float*)d_in[0];
    const int* cid = (const int*)d_in[1];
    const float* pro = (const float*)d_in[2];
    float* out = (float*)d_out;

    char* ws = (char*)d_ws;
    unsigned short* embn = (unsigned short*)ws;                    // 8 MB bf16 [B,D]
    unsigned short* pron = (unsigned short*)(ws + 8388608);        // 16 MB bf16 [K,D]
    float* rowsum = (float*)(ws + 25165824);                       // [B]
    float* rowpos = (float*)(ws + 25198592);                       // [B]
    // EMA buckets alias the pron region — only touched after flash_kernel (stream order):
    // loss_kernel zeroes cnt, ema_count fills, ema_apply reads.
    int* cnt = (int*)(ws + 8388608);                               // [K]
    int* bucket = (int*)(ws + 8388608 + 65536);                    // [K, CAP]

    norm_kernel<<<(B_N + K_N) / 4, 256, 0, stream>>>(emb, pro, embn, pron, rowsum, out);
    pos_kernel<<<B_N / 4, 256, 0, stream>>>(emb, pro, cid, rowpos);
    flash_kernel<<<dim3(B_N / BM, SPLIT), 256, 0, stream>>>(embn, pron, rowsum);
    loss_kernel<<<B_N / 256, 256, 0, stream>>>(rowsum, rowpos, out, cnt);
    ema_count<<<B_N / 256, 256, 0, stream>>>(cid, cnt, bucket);
    ema_apply<<<K_N / 4, 256, 0, stream>>>(emb, pro, cnt, bucket, out + 1);
}

// Round 6
// 204.515 us; speedup vs baseline: 1.8947x; 1.3860x over previous
//
#include <hip/hip_runtime.h>
#include <hip/hip_bf16.h>

// PrototypeConsistentLearning: loss = mean(-pos + lse_neg), new_protos = serial EMA.
// B=8192, D=512, K=16384, T=0.5, momentum=0.9.
// R6: MX-fp8 flash GEMM via mfma_scale_f32_16x16x128_f8f6f4 (2x MFMA rate, half
// staging bytes vs bf16 — guide ladder m145/m148: 874->1628 TF on this structure).
// Normalized values quantized x16 to e4m3 (RNE), unit E8M0 scales (0x7F), epilogue
// un-scales by 2^-8. fp8 LDS rows are 128 B = 32 banks -> XOR-swizzle the 16B
// granule index by row&7 (applied at the global source; gl_lds dest is fixed
// lane*16). Fragment: lane holds k=quad*32..+31 contiguous, 2x ds_read_b128.
// pos/EMA stay exact fp32. R5 pipeline kept: barrier-read-barrier-prefetch-MFMA.

#define B_N 8192
#define D_N 512
#define K_N 16384
#define INV_T 2.0f
#define MOM 0.9f

#define BM 128
#define BN 128
#define BKF 128
#define SPLIT 32
#define TILES ((K_N / SPLIT) / BN)  // 4
#define CHUNKS (D_N / BKF)          // 4
#define CAP 64

typedef __attribute__((ext_vector_type(8))) int intx8;
typedef __attribute__((ext_vector_type(4))) float floatx4;

__device__ __forceinline__ void gl_lds16(const void* g, void* lds) {
    __builtin_amdgcn_global_load_lds(
        (const __attribute__((address_space(1))) void*)g,
        (__attribute__((address_space(3))) void*)lds, 16, 0, 0);
}

// ---- normalize rows (fp32) -> e4m3 fp8 scaled by 16; also zero rowsum/out[0]. ----
__global__ void norm_kernel(const float* __restrict__ emb, const float* __restrict__ pro,
                            unsigned char* __restrict__ embq, unsigned char* __restrict__ proq,
                            float* __restrict__ rowsum, float* __restrict__ out) {
    if (blockIdx.x < 32) rowsum[blockIdx.x * 256 + threadIdx.x] = 0.0f;
    if (blockIdx.x == 32 && threadIdx.x == 0) out[0] = 0.0f;
    int row = blockIdx.x * 4 + (threadIdx.x >> 6);
    int lane = threadIdx.x & 63;
    const float* x;
    unsigned char* o;
    if (row < B_N) {
        x = emb + (size_t)row * D_N;
        o = embq + (size_t)row * D_N;
    } else {
        x = pro + (size_t)(row - B_N) * D_N;
        o = proq + (size_t)(row - B_N) * D_N;
    }
    const float4* xp = (const float4*)(x + lane * 8);
    float4 v0 = xp[0];
    float4 v1 = xp[1];
    float ss = v0.x * v0.x + v0.y * v0.y + v0.z * v0.z + v0.w * v0.w +
               v1.x * v1.x + v1.y * v1.y + v1.z * v1.z + v1.w * v1.w;
    #pragma unroll
    for (int of = 32; of; of >>= 1) ss += __shfl_xor(ss, of);
    float sc = 16.0f / fmaxf(sqrtf(ss), 1e-12f);  // x16: e4m3 keeps full mantissa range
    int w0 = 0, w1 = 0;
    w0 = __builtin_amdgcn_cvt_pk_fp8_f32(v0.x * sc, v0.y * sc, w0, false);
    w0 = __builtin_amdgcn_cvt_pk_fp8_f32(v0.z * sc, v0.w * sc, w0, true);
    w1 = __builtin_amdgcn_cvt_pk_fp8_f32(v1.x * sc, v1.y * sc, w1, false);
    w1 = __builtin_amdgcn_cvt_pk_fp8_f32(v1.z * sc, v1.w * sc, w1, true);
    int2 st = {w0, w1};
    *(int2*)(o + lane * 8) = st;
}

// ---- pos[b] = 2 * dot(emb[b],pro[c]) / (|emb[b]| |pro[c]|), pure fp32 (exact). ----
__global__ void pos_kernel(const float* __restrict__ emb, const float* __restrict__ pro,
                           const int* __restrict__ cid, float* __restrict__ rowpos) {
    int b = blockIdx.x * 4 + (threadIdx.x >> 6);
    int lane = threadIdx.x & 63;
    int c = cid[b];
    const float4* ep = (const float4*)(emb + (size_t)b * D_N + lane * 8);
    const float4* pp = (const float4*)(pro + (size_t)c * D_N + lane * 8);
    float4 e0 = ep[0], e1 = ep[1], p0 = pp[0], p1 = pp[1];
    float dp = e0.x * p0.x + e0.y * p0.y + e0.z * p0.z + e0.w * p0.w +
               e1.x * p1.x + e1.y * p1.y + e1.z * p1.z + e1.w * p1.w;
    float ee = e0.x * e0.x + e0.y * e0.y + e0.z * e0.z + e0.w * e0.w +
               e1.x * e1.x + e1.y * e1.y + e1.z * e1.z + e1.w * e1.w;
    float qq = p0.x * p0.x + p0.y * p0.y + p0.z * p0.z + p0.w * p0.w +
               p1.x * p1.x + p1.y * p1.y + p1.z * p1.z + p1.w * p1.w;
    #pragma unroll
    for (int o = 32; o; o >>= 1) {
        dp += __shfl_xor(dp, o);
        ee += __shfl_xor(ee, o);
        qq += __shfl_xor(qq, o);
    }
    if (lane == 0)
        rowpos[b] = INV_T * dp / (fmaxf(sqrtf(ee), 1e-12f) * fmaxf(sqrtf(qq), 1e-12f));
}

// ---- flash GEMM (MX-fp8): rowsum[b] += sum_k exp(2*dot(emb_n[b], proto_n[k])) ----
__global__ __launch_bounds__(256) void flash_kernel(const unsigned char* __restrict__ embq,
                                                    const unsigned char* __restrict__ proq,
                                                    float* __restrict__ rowsum_g) {
    __shared__ __align__(16) unsigned char As[BM * BKF];  // 16 KB
    __shared__ __align__(16) unsigned char Bs[BN * BKF];  // 16 KB
    const int t = threadIdx.x;
    const int w = t >> 6, lane = t & 63;
    const int quad = lane >> 4, lcol = lane & 15;
    const int wm = w >> 1, wn = w & 1;
    const int rowBase = blockIdx.x * BM;
    const int nBegin = blockIdx.y * (K_N / SPLIT);

    // Fragment LDS offsets (loop-invariant). Logical granules quad*2, quad*2+1 of the
    // 128-B row; stored position = granule ^ (row&7), row&7 == lcol&7 here.
    const int fsw0 = (((quad << 1) | 0) ^ (lcol & 7)) << 4;
    const int fsw1 = (((quad << 1) | 1) ^ (lcol & 7)) << 4;
    const unsigned char* aF = &As[(wm * 64 + lcol) * BKF];
    const unsigned char* bF = &Bs[(wn * 64 + lcol) * BKF];
    // Staging: pass p covers LDS rows p*32 + w*8 + (lane>>3); lane's 16B lands at
    // stored granule lane&7 -> fetch global granule (lane&7)^(lane>>3).
    const int srow = w * 8 + (lane >> 3);
    const int scol = ((lane & 7) ^ (lane >> 3)) << 4;
    const unsigned char* aS = embq + (size_t)(rowBase + srow) * D_N + scol;
    const unsigned char* bS = proq + (size_t)(nBegin + srow) * D_N + scol;

    float rowsum[16];
    #pragma unroll
    for (int i = 0; i < 16; i++) rowsum[i] = 0.0f;

    // issue chunk 0 of tile 0
    #pragma unroll
    for (int p = 0; p < 4; p++) {
        gl_lds16(aS + p * 32 * D_N, &As[p * 4096 + w * 1024]);
        gl_lds16(bS + p * 32 * D_N, &Bs[p * 4096 + w * 1024]);
    }

    for (int tile = 0; tile < TILES; tile++) {
        floatx4 acc[4][4];
        #pragma unroll
        for (int mt = 0; mt < 4; mt++)
            #pragma unroll
            for (int nt = 0; nt < 4; nt++) {
                floatx4 z = {0.0f, 0.0f, 0.0f, 0.0f};
                acc[mt][nt] = z;
            }
        #pragma unroll
        for (int ch = 0; ch < CHUNKS; ch++) {
            __syncthreads();  // staging of chunk `ch` complete
            intx8 af[4], bf[4];
            #pragma unroll
            for (int mt = 0; mt < 4; mt++) {
                int4 lo = *(const int4*)(aF + mt * 16 * BKF + fsw0);
                int4 hi = *(const int4*)(aF + mt * 16 * BKF + fsw1);
                intx8 v = {lo.x, lo.y, lo.z, lo.w, hi.x, hi.y, hi.z, hi.w};
                af[mt] = v;
            }
            #pragma unroll
            for (int nt = 0; nt < 4; nt++) {
                int4 lo = *(const int4*)(bF + nt * 16 * BKF + fsw0);
                int4 hi = *(const int4*)(bF + nt * 16 * BKF + fsw1);
                intx8 v = {lo.x, lo.y, lo.z, lo.w, hi.x, hi.y, hi.z, hi.w};
                bf[nt] = v;
            }
            __syncthreads();  // frags in regs; LDS reusable
            if (ch + 1 < CHUNKS) {
                #pragma unroll
                for (int p = 0; p < 4; p++) {
                    gl_lds16(aS + p * 32 * D_N + (ch + 1) * BKF, &As[p * 4096 + w * 1024]);
                    gl_lds16(bS + p * 32 * D_N + (ch + 1) * BKF, &Bs[p * 4096 + w * 1024]);
                }
            } else if (tile + 1 < TILES) {
                #pragma unroll
                for (int p = 0; p < 4; p++) {
                    gl_lds16(aS + p * 32 * D_N, &As[p * 4096 + w * 1024]);
                    gl_lds16(bS + (size_t)BN * D_N + p * 32 * D_N, &Bs[p * 4096 + w * 1024]);
                }
            }
            // fmt 0 = fp8 e4m3 for A and B; unit scales (E8M0 0x7F = 2^0), any opsel byte.
            #pragma unroll
            for (int mt = 0; mt < 4; mt++)
                #pragma unroll
                for (int nt = 0; nt < 4; nt++)
                    acc[mt][nt] = __builtin_amdgcn_mfma_scale_f32_16x16x128_f8f6f4(
                        af[mt], bf[nt], acc[mt][nt], 0, 0, 0, 0x7F7F7F7F, 0, 0x7F7F7F7F);
        }
        bS += (size_t)BN * D_N;
        // epilogue: C/D layout col=lane&15, row=quad*4+reg; un-scale 16*16 -> 2^-8
        #pragma unroll
        for (int mt = 0; mt < 4; mt++)
            #pragma unroll
            for (int nt = 0; nt < 4; nt++)
                #pragma unroll
                for (int r = 0; r < 4; r++)
                    rowsum[mt * 4 + r] += __expf(acc[mt][nt][r] * (INV_T / 256.0f));
    }
    #pragma unroll
    for (int i = 0; i < 16; i++) {
        #pragma unroll
        for (int o = 1; o < 16; o <<= 1) rowsum[i] += __shfl_xor(rowsum[i], o);
    }
    if (lcol == 0) {
        #pragma unroll
        for (int mt = 0; mt < 4; mt++)
            #pragma unroll
            for (int r = 0; r < 4; r++)
                atomicAdd(&rowsum_g[rowBase + wm * 64 + mt * 16 + quad * 4 + r],
                          rowsum[mt * 4 + r]);
    }
}

// ---- loss partial: 32 blocks, atomicAdd into out[0]; also zero cnt for EMA. ----
__global__ void loss_kernel(const float* __restrict__ rowsum, const float* __restrict__ rowpos,
                            float* __restrict__ out, int* __restrict__ cnt) {
    __shared__ float red[256];
    int t = threadIdx.x;
    int b = blockIdx.x * 256 + t;
    cnt[b * 2] = 0;
    cnt[b * 2 + 1] = 0;
    float p = rowpos[b];
    red[t] = logf(rowsum[b] - __expf(p)) - p;
    __syncthreads();
    for (int o = 128; o; o >>= 1) {
        if (t < o) red[t] += red[t + o];
        __syncthreads();
    }
    if (t == 0) atomicAdd(out, red[0] * (1.0f / (float)B_N));
}

// ---- EMA phase 1: bucket occurrence indices per cluster. ----
__global__ void ema_count(const int* __restrict__ cid, int* __restrict__ cnt,
                          int* __restrict__ bucket) {
    int b = blockIdx.x * 256 + threadIdx.x;
    int c = cid[b];
    int slot = atomicAdd(&cnt[c], 1);
    if (slot < CAP) bucket[c * CAP + slot] = b;
}

// ---- EMA phase 2: one wave per cluster, replay occurrences in ascending b. ----
__global__ void ema_apply(const float* __restrict__ emb, const float* __restrict__ pro,
                          const int* __restrict__ cnt, const int* __restrict__ bucket,
                          float* __restrict__ outp) {
    int k = blockIdx.x * 4 + (threadIdx.x >> 6);
    int lane = threadIdx.x & 63;
    int n = cnt[k];
    n = n < CAP ? n : CAP;
    const float4* pp = (const float4*)(pro + (size_t)k * D_N + lane * 8);
    float4 a0 = pp[0], a1 = pp[1];
    int myb = (lane < n) ? bucket[k * CAP + lane] : 0x7fffffff;
    for (int i = 0; i < n; i++) {
        int m = myb;
        #pragma unroll
        for (int o = 1; o < 64; o <<= 1) {
            int v = __shfl_xor(m, o);
            m = v < m ? v : m;
        }
        const float4* ep = (const float4*)(emb + (size_t)m * D_N + lane * 8);
        float4 e0 = ep[0], e1 = ep[1];
        a0.x = MOM * a0.x + (1.0f - MOM) * e0.x;
        a0.y = MOM * a0.y + (1.0f - MOM) * e0.y;
        a0.z = MOM * a0.z + (1.0f - MOM) * e0.z;
        a0.w = MOM * a0.w + (1.0f - MOM) * e0.w;
        a1.x = MOM * a1.x + (1.0f - MOM) * e1.x;
        a1.y = MOM * a1.y + (1.0f - MOM) * e1.y;
        a1.z = MOM * a1.z + (1.0f - MOM) * e1.z;
        a1.w = MOM * a1.w + (1.0f - MOM) * e1.w;
        if (myb == m) myb = 0x7fffffff;
    }
    float4* op = (float4*)(outp + (size_t)k * D_N + lane * 8);
    op[0] = a0;
    op[1] = a1;
}

extern "C" void kernel_launch(void* const* d_in, const int* in_sizes, int n_in,
                              void* d_out, int out_size, void* d_ws, size_t ws_size,
                              hipStream_t stream) {
    const float* emb = (const float*)d_in[0];
    const int* cid = (const int*)d_in[1];
    const float* pro = (const float*)d_in[2];
    float* out = (float*)d_out;

    char* ws = (char*)d_ws;
    unsigned char* embq = (unsigned char*)ws;                      // 4 MB fp8 [B,D]
    unsigned char* proq = (unsigned char*)(ws + 4194304);          // 8 MB fp8 [K,D]
    float* rowsum = (float*)(ws + 12582912);                       // [B]
    float* rowpos = (float*)(ws + 12615680);                       // [B]
    // EMA buckets alias the proq region — only touched after flash_kernel (stream
    // order): loss_kernel zeroes cnt, ema_count fills, ema_apply reads.
    int* cnt = (int*)(ws + 4194304);                               // [K]
    int* bucket = (int*)(ws + 4194304 + 65536);                    // [K, CAP]

    norm_kernel<<<(B_N + K_N) / 4, 256, 0, stream>>>(emb, pro, embq, proq, rowsum, out);
    pos_kernel<<<B_N / 4, 256, 0, stream>>>(emb, pro, cid, rowpos);
    flash_kernel<<<dim3(B_N / BM, SPLIT), 256, 0, stream>>>(embq, proq, rowsum);
    loss_kernel<<<B_N / 256, 256, 0, stream>>>(rowsum, rowpos, out, cnt);
    ema_count<<<B_N / 256, 256, 0, stream>>>(cid, cnt, bucket);
    ema_apply<<<K_N / 4, 256, 0, stream>>>(emb, pro, cnt, bucket, out + 1);
}